// Round 2
// baseline (689.280 us; speedup 1.0000x reference)
//
#include <hip/hip_runtime.h>
#include <math.h>

// InfoNCE loss: B=4096 rows, N=127 negatives, D=256, fp32.  ~541 MB read-once.
// R5: wave-per-vector contiguous streaming (vs R3/R4's 16x16 groups, both
// stuck at ~330 us kernel time ~= 26% of achievable HBM BW).
// Theory: 16-lane groups make every wave-load 4 scattered 256 B granules at
// 1 KB stride and 16 interleaved per-block streams jumping 16 KB per step
// (~32K concurrent 256B streams device-wide) -> HBM row/channel locality
// lost. The 6.3 TB/s copy ubench (m13) streams contiguous 1 KB per
// wave-load; replicate that shape:
//   - lane l owns floats [4l..4l+3]: one wave-load = contiguous 1 KB
//   - block's 4 waves read 4 consecutive vectors per step = contiguous 4 KB,
//     marching sequentially through the row's 128 KB
//   - 64-lane shuffle reductions (12/vector), off the load path via a
//     4-deep register ring (consume-then-reload keeps ~4 KB/wave in flight)
//   - VGPR ~55 -> 8 waves/SIMD

namespace {
constexpr int B = 4096;
constexpr int N = 127;
constexpr int D = 256;
constexpr int V = N + 1;          // 128 logits per row
constexpr float INV_TEMP = 1.0f / 0.07f;
constexpr float EPS = 1e-12f;

typedef float f32x4 __attribute__((ext_vector_type(4)));

__device__ __forceinline__ float wave_reduce_sum(float v) {
    #pragma unroll
    for (int off = 32; off > 0; off >>= 1) v += __shfl_xor(v, off, 64);
    return v;
}
__device__ __forceinline__ float wave_reduce_max(float v) {
    #pragma unroll
    for (int off = 32; off > 0; off >>= 1) v = fmaxf(v, __shfl_xor(v, off, 64));
    return v;
}
} // namespace

__global__ __launch_bounds__(256) void infonce_rows(
    const float* __restrict__ anchor,
    const float* __restrict__ positive,
    const float* __restrict__ negatives,
    float* __restrict__ row_loss)
{
    const int b    = blockIdx.x;
    const int tid  = threadIdx.x;
    const int lane = tid & 63;    // lane within wave
    const int w    = tid >> 6;    // wave id, 0..3

    __shared__ float scores[V];

    // --- anchor fragment: lane holds floats [4*lane .. 4*lane+3] ---
    f32x4 aa = *reinterpret_cast<const f32x4*>(anchor + (size_t)b * D + lane * 4);
    float asq = aa.x * aa.x + aa.y * aa.y + aa.z * aa.z + aa.w * aa.w;
    asq = wave_reduce_sum(asq);
    const float ainv = 1.0f / fmaxf(sqrtf(asq), EPS);
    aa *= ainv;

    // --- wave w streams vectors v = w + 4*it, it = 0..31.
    // For v >= 1 the vector lives at negatives[(b*N + v - 1)*D]; fold (w-1)
    // into the base so the per-it stride is 4*D floats. For w==0, it==0 the
    // vector is `positive` (base pointer never dereferenced at that slot). ---
    const float* nb = negatives
        + ((ptrdiff_t)b * N + (ptrdiff_t)w - 1) * D + lane * 4;
    const float* p0 = (w == 0) ? (positive + (size_t)b * D + lane * 4) : nb;

    // 4-deep register ring: preload its 0..3
    f32x4 buf[4];
    buf[0] = *reinterpret_cast<const f32x4*>(p0);
    #pragma unroll
    for (int j = 1; j < 4; ++j)
        buf[j] = *reinterpret_cast<const f32x4*>(nb + (size_t)j * 4 * D);

    const float* pn = nb + (size_t)16 * D;   // it = 4..7 chunk base
    for (int c = 0; c < 8; ++c) {
        #pragma unroll
        for (int j = 0; j < 4; ++j) {
            const int it = 4 * c + j;
            const f32x4 x = buf[j];
            if (c < 7)   // consume-then-reload: keep ~4 loads in flight
                buf[j] = *reinterpret_cast<const f32x4*>(pn + (size_t)j * 4 * D);
            float d = aa.x * x.x + aa.y * x.y + aa.z * x.z + aa.w * x.w;
            float s = x.x * x.x + x.y * x.y + x.z * x.z + x.w * x.w;
            d = wave_reduce_sum(d);
            s = wave_reduce_sum(s);
            if (lane == 0)
                scores[w + 4 * it] = d / fmaxf(sqrtf(s), EPS);
        }
        pn += (size_t)16 * D;
    }
    __syncthreads();

    // --- logsumexp over 128 logits (first wave) ---
    if (tid < 64) {
        const float s0 = scores[tid]      * INV_TEMP;
        const float s1 = scores[tid + 64] * INV_TEMP;
        float m = wave_reduce_max(fmaxf(s0, s1));
        float e = expf(s0 - m) + expf(s1 - m);
        e = wave_reduce_sum(e);
        if (tid == 0)
            row_loss[b] = m + logf(e) - scores[0] * INV_TEMP;
    }
}

__global__ __launch_bounds__(256) void reduce_mean(
    const float* __restrict__ row_loss, float* __restrict__ out)
{
    __shared__ float wsum[4];
    const int tid  = threadIdx.x;
    const int wave = tid >> 6;
    const int lane = tid & 63;

    float s = 0.0f;
    for (int i = tid; i < B; i += 256) s += row_loss[i];
    s = wave_reduce_sum(s);
    if (lane == 0) wsum[wave] = s;
    __syncthreads();
    if (tid == 0)
        out[0] = (wsum[0] + wsum[1] + wsum[2] + wsum[3]) * (1.0f / (float)B);
}

extern "C" void kernel_launch(void* const* d_in, const int* in_sizes, int n_in,
                              void* d_out, int out_size, void* d_ws, size_t ws_size,
                              hipStream_t stream) {
    const float* anchor    = (const float*)d_in[0];
    const float* positive  = (const float*)d_in[1];
    const float* negatives = (const float*)d_in[2];
    float* out      = (float*)d_out;
    float* row_loss = (float*)d_ws;   // B floats = 16 KB scratch

    infonce_rows<<<B, 256, 0, stream>>>(anchor, positive, negatives, row_loss);
    reduce_mean<<<1, 256, 0, stream>>>(row_loss, out);
}

// Round 5
// 680.056 us; speedup vs baseline: 1.0136x; 1.0136x over previous
//
#include <hip/hip_runtime.h>
#include <math.h>

// InfoNCE loss: B=4096 rows, N=127 negatives, D=256, fp32.  ~541 MB read-once.
// R7 = R6 minus nontemporal loads.
// Infra forensics: every bench submission containing __builtin_nontemporal_load
// failed with "container failed twice" (3/3: R0,R3,R4); every one without it
// passed (2/2: R1,R2). Suspect nt-load path crashes the harness/rocprof replay
// on this container image -> use plain f32x4 loads (measured cost <= 4%).
// Theory under test (unchanged from R6): R3/R4/R5 all sat at ~330 us kernel
// (~26% of achievable HBM BW) regardless of access pattern -> effective-
// occupancy collapse from VGPR ballooning / scratch spills. Fix by
// construction:
//   - __launch_bounds__(256, 6): 6 blocks/CU pinned, 85-VGPR budget
//   - no register arrays: scalar dot/sq temps, group-reduced + stored to LDS
//     inside the loop; 4 named f32x4 per-iteration temps (~50 VGPR total)
//   - #pragma unroll 1 pins the streaming loop (no unroll ballooning)

namespace {
constexpr int B = 4096;
constexpr int N = 127;
constexpr int D = 256;
constexpr int V = N + 1;          // 128 logits per row
constexpr float INV_TEMP = 1.0f / 0.07f;
constexpr float EPS = 1e-12f;

typedef float f32x4 __attribute__((ext_vector_type(4)));

__device__ __forceinline__ float group16_reduce_sum(float v) {
    #pragma unroll
    for (int off = 1; off < 16; off <<= 1) v += __shfl_xor(v, off, 64);
    return v;
}
__device__ __forceinline__ float wave_reduce_sum(float v) {
    #pragma unroll
    for (int off = 32; off > 0; off >>= 1) v += __shfl_xor(v, off, 64);
    return v;
}
__device__ __forceinline__ float wave_reduce_max(float v) {
    #pragma unroll
    for (int off = 32; off > 0; off >>= 1) v = fmaxf(v, __shfl_xor(v, off, 64));
    return v;
}
__device__ __forceinline__ f32x4 ld4(const float* p) {
    return *reinterpret_cast<const f32x4*>(p);
}
__device__ __forceinline__ float dot4(const f32x4 a, const f32x4 b) {
    return a.x * b.x + a.y * b.y + a.z * b.z + a.w * b.w;
}
} // namespace

__global__ __launch_bounds__(256, 6) void infonce_rows(
    const float* __restrict__ anchor,
    const float* __restrict__ positive,
    const float* __restrict__ negatives,
    float* __restrict__ row_loss)
{
    const int b   = blockIdx.x;
    const int tid = threadIdx.x;
    const int sub = tid & 15;   // lane within 16-group
    const int g   = tid >> 4;   // 16-group id, 0..15

    __shared__ float scores[V];

    // --- anchor: group-lane holds floats {i*64 + sub*4 .. +3}, i=0..3 ---
    const float* arow = anchor + (size_t)b * D + sub * 4;
    f32x4 aa0 = ld4(arow);
    f32x4 aa1 = ld4(arow + 64);
    f32x4 aa2 = ld4(arow + 128);
    f32x4 aa3 = ld4(arow + 192);
    float asq = dot4(aa0, aa0) + dot4(aa1, aa1) + dot4(aa2, aa2) + dot4(aa3, aa3);
    asq = group16_reduce_sum(asq);
    const float ainv = 1.0f / fmaxf(sqrtf(asq), EPS);
    aa0 *= ainv; aa1 *= ainv; aa2 *= ainv; aa3 *= ainv;

    // --- group g scores vectors v = g + 16*it, it = 0..7.
    // For v >= 1 the vector is negatives[(b*N + v - 1)*D]; fold (g-1) into
    // the base. For g==0 the base is only dereferenced from it>=1. ---
    const float* nb = negatives
        + ((ptrdiff_t)b * N + (ptrdiff_t)g - 1) * D + sub * 4;

    // it = 0 (positive for group 0)
    {
        const float* p = (g == 0) ? (positive + (size_t)b * D + sub * 4) : nb;
        const f32x4 x0 = ld4(p);
        const f32x4 x1 = ld4(p + 64);
        const f32x4 x2 = ld4(p + 128);
        const f32x4 x3 = ld4(p + 192);
        float d = dot4(aa0, x0) + dot4(aa1, x1) + dot4(aa2, x2) + dot4(aa3, x3);
        float s = dot4(x0, x0) + dot4(x1, x1) + dot4(x2, x2) + dot4(x3, x3);
        d = group16_reduce_sum(d);
        s = group16_reduce_sum(s);
        if (sub == 0) scores[g] = d / fmaxf(sqrtf(s), EPS);
    }

    // its 1..7: pure streaming, minimal live state
    #pragma unroll 1
    for (int it = 1; it < 8; ++it) {
        const float* p = nb + (size_t)it * 16 * D;
        const f32x4 x0 = ld4(p);
        const f32x4 x1 = ld4(p + 64);
        const f32x4 x2 = ld4(p + 128);
        const f32x4 x3 = ld4(p + 192);
        float d = dot4(aa0, x0) + dot4(aa1, x1) + dot4(aa2, x2) + dot4(aa3, x3);
        float s = dot4(x0, x0) + dot4(x1, x1) + dot4(x2, x2) + dot4(x3, x3);
        d = group16_reduce_sum(d);
        s = group16_reduce_sum(s);
        if (sub == 0) scores[g + 16 * it] = d / fmaxf(sqrtf(s), EPS);
    }
    __syncthreads();

    // --- logsumexp over 128 logits (first wave) ---
    if (tid < 64) {
        const float s0 = scores[tid]      * INV_TEMP;
        const float s1 = scores[tid + 64] * INV_TEMP;
        float m = wave_reduce_max(fmaxf(s0, s1));
        float e = expf(s0 - m) + expf(s1 - m);
        e = wave_reduce_sum(e);
        if (tid == 0)
            row_loss[b] = m + logf(e) - scores[0] * INV_TEMP;
    }
}

__global__ __launch_bounds__(256) void reduce_mean(
    const float* __restrict__ row_loss, float* __restrict__ out)
{
    __shared__ float wsum[4];
    const int tid  = threadIdx.x;
    const int wave = tid >> 6;
    const int lane = tid & 63;

    float s = 0.0f;
    for (int i = tid; i < B; i += 256) s += row_loss[i];
    s = wave_reduce_sum(s);
    if (lane == 0) wsum[wave] = s;
    __syncthreads();
    if (tid == 0)
        out[0] = (wsum[0] + wsum[1] + wsum[2] + wsum[3]) * (1.0f / (float)B);
}

extern "C" void kernel_launch(void* const* d_in, const int* in_sizes, int n_in,
                              void* d_out, int out_size, void* d_ws, size_t ws_size,
                              hipStream_t stream) {
    const float* anchor    = (const float*)d_in[0];
    const float* positive  = (const float*)d_in[1];
    const float* negatives = (const float*)d_in[2];
    float* out      = (float*)d_out;
    float* row_loss = (float*)d_ws;   // B floats = 16 KB scratch

    infonce_rows<<<B, 256, 0, stream>>>(anchor, positive, negatives, row_loss);
    reduce_mean<<<1, 256, 0, stream>>>(row_loss, out);
}